// Round 2
// baseline (22.537 us; speedup 1.0000x reference)
//
#include <hip/hip_runtime.h>

// ---------------------------------------------------------------------------
// FFT_Conv_Layer == 3x3 "same" spatial conv with flipped REAL filter plane:
//   out[b,o,y,x] = sum_{i,ky,kx} filts[0,i,o,ky,kx,0] * img[b,i,y+1-ky,x+1-kx]
// (imag filter plane only reaches the imaginary output, dropped by .real;
//  circular conv at S=66 == full linear conv; crop [1:-1] => "same" conv.)
//
// R1 lesson: 9.8MB of d_ws overflowed ws_size -> OOB writes corrupted inputs
// across timed replays. Now d_ws use = 73,728 B (weight fragments only);
// the image is staged f32->f16 directly into LDS by the conv kernel.
// ---------------------------------------------------------------------------

typedef _Float16 f16x8 __attribute__((ext_vector_type(8)));
typedef float    f32x4 __attribute__((ext_vector_type(4)));

#define NB 16
#define NC 64
#define NH 64
#define NW 64
#define CHUNKS 528                 // 66 xp positions * 8 channel-chunks per slab
#define SLAB_BYTES (CHUNKS * 16)   // 8448 B per image row slab
#define WF_HALFS (9 * 2 * 4 * 64 * 8)  // taps * kc * n * lane * elem = 36864

// ---------------------------------------------------------------------------
// prep_w: filts [1][inC][outC][3][3][2] f32 -> per-fragment f16 weights
//   Wf[t][kc][n][lane][e] = filts[0][ i=kc*32+(l/16)*8+e ][ o=n*16+l%16 ][ky][kx][0]
// Same (lane-group,e)->k labeling as the A fragments, so the MFMA k-pairing
// is consistent regardless of the hardware's internal k bijection.
// ---------------------------------------------------------------------------
__global__ __launch_bounds__(256) void prep_w(const float* __restrict__ filts,
                                              _Float16* __restrict__ wf) {
    const int f = blockIdx.x * 256 + threadIdx.x;
    if (f >= WF_HALFS) return;
    const int e  = f & 7;
    const int l  = (f >> 3) & 63;
    const int n  = (f >> 9) & 3;
    const int kc = (f >> 11) & 1;
    const int t  = f >> 12;              // 0..8
    const int i  = kc * 32 + (l >> 4) * 8 + e;
    const int o  = n * 16 + (l & 15);
    const int ky = t / 3, kx = t % 3;
    wf[f] = (_Float16)filts[(((i * 64 + o) * 3 + ky) * 3 + kx) * 2];
}

// ---------------------------------------------------------------------------
// conv_direct: 512 blocks = (b, 2-row group), 4 waves.
//   Staging: wave w fills LDS slab w (row yp=y0+w, i.e. image y=y0+w-1):
//     lane=x loads 8 channels (coalesced 256B per channel), cvt f16, one
//     swizzled ds_write_b128 per 8-channel chunk. chunk = xp*8 + (ci^(xp&7))
//     balances b128 ops across all 32 banks (8 lanes per 4-bank group).
//   Compute: wave w owns (row = w>>1, outC half = w&1): 4x2 16x16 frags,
//     K-loop = 3ky*3kx*2kc, per step 4 A ds_reads + 2 B global loads + 8 MFMA.
//   C/D layout (m89/m91-verified): o = n*16 + (lane&15), x = m*16+(lane>>4)*4+j
// ---------------------------------------------------------------------------
__global__ __launch_bounds__(256, 2) void conv_direct(const float* __restrict__ imgs,
                                                      const _Float16* __restrict__ wf,
                                                      float* __restrict__ out) {
    __shared__ uint4 ldsb[4 * SLAB_BYTES / 16];   // 33,792 B
    char* lds = reinterpret_cast<char*>(ldsb);
    const int bid = blockIdx.x;
    const int b   = bid >> 5;
    const int y0  = (bid & 31) << 1;     // first output row of this block
    const int tid = threadIdx.x;
    const int w   = tid >> 6;
    const int l   = tid & 63;
    const int h   = l >> 4;              // k-chunk lane group
    const int r   = l & 15;              // A-row / B-col within fragment

    // ---- stage slab rs = w : image row y = y0 + w - 1, all 64 channels ----
    {
        const int rs = w;
        const int y  = y0 + rs - 1;
        const bool yv = ((unsigned)y < (unsigned)NH);
        char* slab = lds + rs * SLAB_BYTES;
        #pragma unroll
        for (int ci = 0; ci < 8; ++ci) {
            f16x8 v;
            if (yv) {
                const float* src = imgs + (((size_t)(b * NC + ci * 8)) * NH + y) * NW + l;
                #pragma unroll
                for (int k = 0; k < 8; ++k) v[k] = (_Float16)src[(size_t)k * NH * NW];
            } else {
                #pragma unroll
                for (int k = 0; k < 8; ++k) v[k] = (_Float16)0.f;
            }
            const int xp = l + 1;                         // lane covers x = l
            const int chunk = xp * 8 + (ci ^ (xp & 7));
            *reinterpret_cast<f16x8*>(slab + chunk * 16) = v;
            if (l < 2) {                                  // pad columns xp = 0, 65
                const int xp2 = l ? 65 : 0;
                const int c2  = xp2 * 8 + (ci ^ (xp2 & 7));
                f16x8 z;
                #pragma unroll
                for (int k = 0; k < 8; ++k) z[k] = (_Float16)0.f;
                *reinterpret_cast<f16x8*>(slab + c2 * 16) = z;
            }
        }
    }
    __syncthreads();

    const int row = w >> 1;              // output row offset within group
    const int oh  = w & 1;               // outC half (0..1)

    f32x4 acc[4][2];
    #pragma unroll
    for (int m = 0; m < 4; ++m)
        #pragma unroll
        for (int n = 0; n < 2; ++n)
            acc[m][n] = f32x4{0.f, 0.f, 0.f, 0.f};

    #pragma unroll
    for (int ky = 0; ky < 3; ++ky) {
        const char* slab = lds + (row + 2 - ky) * SLAB_BYTES;   // rs in 0..3
        #pragma unroll
        for (int kx = 0; kx < 3; ++kx) {
            const _Float16* wft = wf + (size_t)(ky * 3 + kx) * (2 * 4 * 64 * 8);
            #pragma unroll
            for (int kc = 0; kc < 2; ++kc) {
                f16x8 a[4], bb[2];
                #pragma unroll
                for (int m = 0; m < 4; ++m) {
                    const int xp = m * 16 + r + 2 - kx;          // 0..65
                    const int chunk = xp * 8 + (((kc << 2) + h) ^ (xp & 7));
                    a[m] = *reinterpret_cast<const f16x8*>(slab + chunk * 16);
                }
                #pragma unroll
                for (int n = 0; n < 2; ++n)
                    bb[n] = *reinterpret_cast<const f16x8*>(
                        wft + ((size_t)((kc << 2) + (oh * 2 + n)) * 64 + l) * 8);
                #pragma unroll
                for (int m = 0; m < 4; ++m)
                    #pragma unroll
                    for (int n = 0; n < 2; ++n)
                        acc[m][n] = __builtin_amdgcn_mfma_f32_16x16x32_f16(a[m], bb[n], acc[m][n], 0, 0, 0);
            }
        }
    }

    const int y = y0 + row;
    #pragma unroll
    for (int m = 0; m < 4; ++m) {
        const int x0 = m * 16 + h * 4;
        #pragma unroll
        for (int n = 0; n < 2; ++n) {
            const int o = oh * 32 + n * 16 + r;
            *reinterpret_cast<f32x4*>(out + (((size_t)(b * 64 + o) * 64 + y) * 64) + x0) = acc[m][n];
        }
    }
}

extern "C" void kernel_launch(void* const* d_in, const int* in_sizes, int n_in,
                              void* d_out, int out_size, void* d_ws, size_t ws_size,
                              hipStream_t stream) {
    const float* imgs  = (const float*)d_in[0];   // [16][64][64][64] f32
    const float* filts = (const float*)d_in[1];   // [1][64][64][3][3][2] f32
    float* out = (float*)d_out;                   // [16][64][64][64] f32
    _Float16* wfb = (_Float16*)d_ws;              // 73,728 B only

    hipLaunchKernelGGL(prep_w, dim3((WF_HALFS + 255) / 256), dim3(256), 0, stream, filts, wfb);
    hipLaunchKernelGGL(conv_direct, dim3(NB * 32), dim3(256), 0, stream, imgs, wfb, out);
}